// Round 8
// baseline (725.494 us; speedup 1.0000x reference)
//
#include <hip/hip_runtime.h>
#include <hip/hip_bf16.h>

#define N_FEAT 3072
#define LATENT 128
#define LOG2PI 1.8378770664093453f

typedef __attribute__((ext_vector_type(8))) short short8;
typedef __attribute__((ext_vector_type(4))) float f32x4;

__device__ __forceinline__ unsigned short f2bf(float x) {
  unsigned int u = __float_as_uint(x);
  u += 0x7FFFu + ((u >> 16) & 1u);
  return (unsigned short)(u >> 16);
}

typedef __attribute__((address_space(1))) const void gas_void;
typedef __attribute__((address_space(3))) void las_void;
__device__ __forceinline__ void gld_lds16(const void* g, void* s) {
  __builtin_amdgcn_global_load_lds((gas_void*)g, (las_void*)s, 16, 0, 0);
}

// ===========================================================================
// k_prep: blocks 0..47: Mp[b] = Wchunk^T Wchunk partial (direct store) +
//         Wt[n][k] = bf16(W[k][n])   (round-5/7 proven)
// ===========================================================================
__global__ __launch_bounds__(256) void k_prep(const float* __restrict__ W,
                                              float* __restrict__ Mp,
                                              unsigned short* __restrict__ Wt) {
  __shared__ __align__(16) float Ws[64 * 128];
  int t = threadIdx.x;
  int k0 = blockIdx.x * 64;
  const float* src = W + (size_t)k0 * 128;
#pragma unroll
  for (int c = 0; c < 8; ++c)
    ((float4*)Ws)[t + 256 * c] = ((const float4*)src)[t + 256 * c];
  __syncthreads();
  int tr = t >> 4, tc = t & 15;
  float acc[8][8];
#pragma unroll
  for (int r = 0; r < 8; ++r)
#pragma unroll
    for (int c = 0; c < 8; ++c) acc[r][c] = 0.f;
#pragma unroll 2
  for (int k = 0; k < 64; ++k) {
    f32x4 a0 = *(f32x4*)&Ws[k * 128 + 8 * tr];
    f32x4 a1 = *(f32x4*)&Ws[k * 128 + 8 * tr + 4];
    f32x4 b0 = *(f32x4*)&Ws[k * 128 + 8 * tc];
    f32x4 b1 = *(f32x4*)&Ws[k * 128 + 8 * tc + 4];
    float av[8] = {a0.x, a0.y, a0.z, a0.w, a1.x, a1.y, a1.z, a1.w};
    float bv[8] = {b0.x, b0.y, b0.z, b0.w, b1.x, b1.y, b1.z, b1.w};
#pragma unroll
    for (int r = 0; r < 8; ++r)
#pragma unroll
      for (int c = 0; c < 8; ++c) acc[r][c] = fmaf(av[r], bv[c], acc[r][c]);
  }
  float* dst = Mp + (size_t)blockIdx.x * 16384 + (size_t)(8 * tr) * 128 + 8 * tc;
#pragma unroll
  for (int r = 0; r < 8; ++r) {
    *(f32x4*)(dst + r * 128) = (f32x4){acc[r][0], acc[r][1], acc[r][2], acc[r][3]};
    *(f32x4*)(dst + r * 128 + 4) = (f32x4){acc[r][4], acc[r][5], acc[r][6], acc[r][7]};
  }
  int n = t >> 1, h = t & 1;
  unsigned pk[16];
#pragma unroll
  for (int c = 0; c < 16; ++c)
    pk[c] = (unsigned)f2bf(Ws[(h * 32 + 2 * c) * 128 + n]) |
            ((unsigned)f2bf(Ws[(h * 32 + 2 * c + 1) * 128 + n]) << 16);
  uint4* wd = (uint4*)(Wt + (size_t)n * N_FEAT + k0 + h * 32);
#pragma unroll
  for (int c = 0; c < 4; ++c)
    wd[c] = make_uint4(pk[4 * c], pk[4 * c + 1], pk[4 * c + 2], pk[4 * c + 3]);
}

// ===========================================================================
// k_red: M = sum of 48 gram partials (proven)
// ===========================================================================
__global__ __launch_bounds__(256) void k_red(const float* __restrict__ Mp,
                                             float* __restrict__ M) {
  int i = blockIdx.x * 256 + threadIdx.x;
  float s = 0.f;
#pragma unroll
  for (int p = 0; p < 48; ++p) s += Mp[(size_t)p * 16384 + i];
  M[i] = s;
}

// ===========================================================================
// inverse: Gauss-Jordan of (M + sigma^2 I) in place, logdet -> scal
// (proven body; t<256 active; runs at s_setprio(1) in its own block)
// ===========================================================================
__device__ __forceinline__ void inverse_body(char* smem, int t, float* M,
                                             float* scal,
                                             const float* log_var) {
  float* sh = (float*)smem;
  float* PR = sh;        // prow[2][128]
  float* PC = sh + 256;  // pcol[2][128]
  float* DB = sh + 512;  // dbuf[2]
  float* DG = sh + 514;  // diag[128]
  float* RD = sh + 642;  // red[2]
  bool act = t < 256;
  int itr = t >> 4, itc = t & 15;
  float lv = log_var[0];
  float sig2 = expf(lv);
  float a[8][8];
  if (act) {
    const float* srcM = M + (size_t)(8 * itr) * 128 + 8 * itc;
#pragma unroll
    for (int r = 0; r < 8; ++r) {
      f32x4 v0 = *(const f32x4*)(srcM + r * 128);
      f32x4 v1 = *(const f32x4*)(srcM + r * 128 + 4);
      a[r][0] = v0.x; a[r][1] = v0.y; a[r][2] = v0.z; a[r][3] = v0.w;
      a[r][4] = v1.x; a[r][5] = v1.y; a[r][6] = v1.z; a[r][7] = v1.w;
    }
    if (itr == itc) {
#pragma unroll
      for (int r = 0; r < 8; ++r) a[r][r] += sig2;
    }
    if (itr == 0) {
#pragma unroll
      for (int c = 0; c < 8; ++c) PR[8 * itc + c] = a[0][c];
    }
    if (itc == 0) {
#pragma unroll
      for (int r = 0; r < 8; ++r) PC[8 * itr + r] = a[r][0];
    }
    if (t == 0) DB[0] = a[0][0];
  }
  __syncthreads();
  for (int kb = 0; kb < 16; ++kb) {
#pragma unroll
    for (int lk = 0; lk < 8; ++lk) {
      const int k = kb * 8 + lk;
      const int buf = k & 1;
      if (act) {
        float d = DB[buf];
        if (t == 0) DG[k] = d;
        float p = 1.0f / d;
        float pr[8], pc[8];
#pragma unroll
        for (int c = 0; c < 8; ++c) pr[c] = PR[buf * 128 + 8 * itc + c] * p;
#pragma unroll
        for (int r = 0; r < 8; ++r) pc[r] = PC[buf * 128 + 8 * itr + r];
#pragma unroll
        for (int r = 0; r < 8; ++r)
#pragma unroll
          for (int c = 0; c < 8; ++c) a[r][c] = fmaf(-pc[r], pr[c], a[r][c]);
        bool myrow = (itr == (k >> 3));
        bool mycol = (itc == (k >> 3));
        if (myrow) {
#pragma unroll
          for (int c = 0; c < 8; ++c) a[lk][c] = pr[c];
        }
        if (mycol) {
#pragma unroll
          for (int r = 0; r < 8; ++r) a[r][lk] = -p * pc[r];
        }
        if (myrow && mycol) a[lk][lk] = p;
        if (k + 1 < 128) {
          const int nb = buf ^ 1;
          const int nl = (lk + 1) & 7;
          const int nr = (k + 1) >> 3;
          if (itr == nr) {
#pragma unroll
            for (int c = 0; c < 8; ++c) PR[nb * 128 + 8 * itc + c] = a[nl][c];
          }
          if (itc == nr) {
#pragma unroll
            for (int r = 0; r < 8; ++r) PC[nb * 128 + 8 * itr + r] = a[r][nl];
          }
          if (itr == nr && itc == nr) DB[nb] = a[nl][nl];
        }
      }
      __syncthreads();
    }
  }
  if (act) {
    float* dst = M + (size_t)(8 * itr) * 128 + 8 * itc;
#pragma unroll
    for (int r = 0; r < 8; ++r) {
      f32x4 v0 = {a[r][0], a[r][1], a[r][2], a[r][3]};
      f32x4 v1 = {a[r][4], a[r][5], a[r][6], a[r][7]};
      *(f32x4*)(dst + r * 128) = v0;
      *(f32x4*)(dst + r * 128 + 4) = v1;
    }
  }
  float ld = 0.f;
  if (t < 128) ld = logf(DG[t]);
#pragma unroll
  for (int o = 1; o < 64; o <<= 1) ld += __shfl_xor(ld, o);
  if (t == 0) RD[0] = ld;
  if (t == 64) RD[1] = ld;
  __syncthreads();
  if (t == 0) {
    scal[0] = -0.5f * (N_FEAT * LOG2PI + (float)(N_FEAT - LATENT) * lv +
                       (RD[0] + RD[1]));
    scal[1] = expf(-lv);
  }
}

// ===========================================================================
// gemm_body: one 32-row x K-half tile. 512 thr, BK=128, 12 iters.
// LDS 48 KB: A double-buffered (2x8 KB, 1 barrier/iter), B SINGLE-buffered
// 32 KB — B is wave-private (wave w DMAs AND reads only rows w*16..w*16+15),
// so B sync is per-wave: lgkmcnt(0) after mma (reads drained before re-DMA),
// vmcnt(4) after barrier (DMA landed before next mma). 48 KB -> 3 blocks/CU,
// so grid 513 is fully co-resident (inverse overlaps from t=0).
// ===========================================================================
__device__ __forceinline__ void gemm_body(char* smem, int rg, int half, int t,
                                          const float* ex, const float* mean,
                                          const unsigned short* Wt, float* Tp,
                                          float* sqp) {
  char* As = smem;            // [2][32][128] ushort = 2 x 8 KB
  char* Bs = smem + 16384;    // [128][128] ushort = 32 KB (single buffer)
  int r0 = rg * 32;
  int tg0 = half * 12;
  int lane = t & 63, w = t >> 6;

  int arow = t >> 4, ag = t & 15;
  const float* ep = ex + (size_t)(r0 + arow) * N_FEAT + (size_t)tg0 * 128 + ag * 8;
  const float* mp = mean + (size_t)tg0 * 128 + ag * 8;
  int awoff = arow * 256 + ((ag & 8) + ((ag + arow) & 7)) * 16;

  int sp = lane & 15, rl = lane >> 4;
  const unsigned short* bsrc[4];
#pragma unroll
  for (int j = 0; j < 4; ++j) {
    int n = w * 16 + j * 4 + rl;
    int s = (sp & 8) | ((sp - n) & 7);
    bsrc[j] = Wt + (size_t)n * N_FEAT + (size_t)tg0 * 128 + s * 8;
  }
  char* ldsB = Bs + (size_t)w * 4096;   // wave-private 16-row region

  int fr = lane & 15, fq = lane >> 4;
  int aoff0[4], aoff1[4], boff[4];
#pragma unroll
  for (int kk = 0; kk < 4; ++kk) {
    int sI = kk * 4 + fq;
    aoff0[kk] = fr * 256 + ((sI & 8) + ((sI + fr) & 7)) * 16;
    int ar1 = 16 + fr;
    aoff1[kk] = ar1 * 256 + ((sI & 8) + ((sI + ar1) & 7)) * 16;
    int n = w * 16 + fr;
    boff[kk] = n * 256 + ((sI & 8) + ((sI + n) & 7)) * 16;
  }

  f32x4 acc0 = {0.f, 0.f, 0.f, 0.f}, acc1 = {0.f, 0.f, 0.f, 0.f};
  float sq = 0.f;
  float4 e, e2, m, m2;   // single A register set (consume-then-reload)

  auto loadA = [&](int it) {
    const float* p = ep + (size_t)it * 128;
    const float* q = mp + (size_t)it * 128;
    e  = *(const float4*)p;  e2 = *(const float4*)(p + 4);
    m  = *(const float4*)q;  m2 = *(const float4*)(q + 4);
  };
  auto packA = [&](int bufN) {
    float r0_ = e.x - m.x,   r1_ = e.y - m.y,   r2_ = e.z - m.z,   r3_ = e.w - m.w;
    float r4_ = e2.x - m2.x, r5_ = e2.y - m2.y, r6_ = e2.z - m2.z, r7_ = e2.w - m2.w;
    sq = fmaf(r0_, r0_, sq); sq = fmaf(r1_, r1_, sq);
    sq = fmaf(r2_, r2_, sq); sq = fmaf(r3_, r3_, sq);
    sq = fmaf(r4_, r4_, sq); sq = fmaf(r5_, r5_, sq);
    sq = fmaf(r6_, r6_, sq); sq = fmaf(r7_, r7_, sq);
    uint4 pa;
    pa.x = (unsigned)f2bf(r0_) | ((unsigned)f2bf(r1_) << 16);
    pa.y = (unsigned)f2bf(r2_) | ((unsigned)f2bf(r3_) << 16);
    pa.z = (unsigned)f2bf(r4_) | ((unsigned)f2bf(r5_) << 16);
    pa.w = (unsigned)f2bf(r6_) | ((unsigned)f2bf(r7_) << 16);
    *(uint4*)(As + bufN * 8192 + awoff) = pa;
  };
  auto issueB = [&](int it) {
#pragma unroll
    for (int j = 0; j < 4; ++j)
      gld_lds16(bsrc[j] + (size_t)it * 128, ldsB + j * 1024);
  };
  auto mma = [&](int bufA) {
    char* Ab = As + bufA * 8192;
#pragma unroll
    for (int kk = 0; kk < 4; ++kk) {
      short8 a0 = *(const short8*)(Ab + aoff0[kk]);
      short8 a1 = *(const short8*)(Ab + aoff1[kk]);
      short8 b  = *(const short8*)(Bs + boff[kk]);
      acc0 = __builtin_amdgcn_mfma_f32_16x16x32_bf16(a0, b, acc0, 0, 0, 0);
      acc1 = __builtin_amdgcn_mfma_f32_16x16x32_bf16(a1, b, acc1, 0, 0, 0);
    }
  };

  // ---- prologue: A(0) packed to buf0; B(0) DMA; A(1) regs in flight ----
  loadA(0);
  packA(0);                                 // implicit wait on loadA(0)
  __builtin_amdgcn_sched_barrier(0);
  issueB(0);                                // 4 DMA (older than loadA(1))
  loadA(1);
  asm volatile("s_waitcnt lgkmcnt(0)" ::: "memory");
  __builtin_amdgcn_s_barrier();
  asm volatile("s_waitcnt vmcnt(4)" ::: "memory");  // B(0) landed; A(1) in flight
  __builtin_amdgcn_sched_barrier(0);

  // ---- main loop: single barrier/iter; B synced per-wave by counts ----
#pragma unroll
  for (int it = 0; it < 11; ++it) {
    mma(it & 1);                            // reads A buf, own B rows
    asm volatile("s_waitcnt lgkmcnt(0)" ::: "memory");  // B reads drained
    __builtin_amdgcn_sched_barrier(0);
    issueB(it + 1);                         // overwrite own B region
    __builtin_amdgcn_sched_barrier(0);      // keep DMA issue before pack
    packA((it + 1) & 1);                    // waits loadA(it+1) via vmcnt(4)
    loadA(it + 2 <= 11 ? it + 2 : 11);      // clamped tail reload (harmless)
    asm volatile("s_waitcnt lgkmcnt(0)" ::: "memory");
    __builtin_amdgcn_s_barrier();
    asm volatile("s_waitcnt vmcnt(4)" ::: "memory");  // B(it+1) landed
    __builtin_amdgcn_sched_barrier(0);
  }
  mma(1);                                   // tile 11 (buf 1)

  // ---- sumsq partial ----
  sq += __shfl_xor(sq, 1); sq += __shfl_xor(sq, 2);
  sq += __shfl_xor(sq, 4); sq += __shfl_xor(sq, 8);
  if (ag == 0) sqp[half * 8192 + r0 + arow] = sq;

  // ---- Tp partial store (D layout col=lane&15, row=fq*4+reg) ----
  float* tp = Tp + (size_t)half * 1048576 +
              (size_t)(r0 + fq * 4) * 128 + w * 16 + fr;
#pragma unroll
  for (int ii = 0; ii < 4; ++ii) {
    tp[(size_t)ii * 128] = acc0[ii];
    tp[(size_t)ii * 128 + 2048] = acc1[ii];
  }
}

// ===========================================================================
// k_gemm: 513 blocks, all co-resident (48 KB LDS -> 3 blocks/CU capacity).
//   block 0: inverse only, at raised wave priority (overlaps the tiles).
//   blocks 1..512: one flat 12-iter tile each (no dual, no serial chain).
// ===========================================================================
__global__ __launch_bounds__(512, 6) void k_gemm(
    const float* __restrict__ ex, const float* __restrict__ mean,
    const unsigned short* __restrict__ Wt, float* __restrict__ M,
    float* __restrict__ scal, const float* __restrict__ lv,
    float* __restrict__ Tp, float* __restrict__ sqp) {
  __shared__ __align__(16) char smem[49152];
  int bid = blockIdx.x, t = threadIdx.x;
  if (bid == 0) {
    __builtin_amdgcn_s_setprio(1);
    inverse_body(smem, t, M, scal, lv);
    __builtin_amdgcn_s_setprio(0);
    return;
  }
  int g = bid - 1;                 // 0..511
  gemm_body(smem, g & 255, g >> 8, t, ex, mean, Wt, Tp, sqp);
}

// ===========================================================================
// k_epi: 256 blocks x 32 rows: t = Tp0+Tp1; quad = t^T Minv t;
//        out = scal0 - 0.5*scal1*(sumsq - quad)   (proven)
// ===========================================================================
__global__ __launch_bounds__(256) void k_epi(const float* __restrict__ Tp,
                                             const float* __restrict__ sqp,
                                             const float* __restrict__ Minv,
                                             const float* __restrict__ scal,
                                             float* __restrict__ out) {
  __shared__ __align__(16) float Ts[32][132];
  __shared__ float rs[32];
  int t = threadIdx.x;
  int r0 = blockIdx.x * 32;
  int sr = t >> 3, sseg = t & 7;
  const float* tp0 = Tp + (size_t)(r0 + sr) * 128 + sseg * 16;
  const float* tp1 = tp0 + 1048576;
#pragma unroll
  for (int c = 0; c < 4; ++c) {
    float4 v0 = *(const float4*)(tp0 + c * 4);
    float4 v1 = *(const float4*)(tp1 + c * 4);
    *(f32x4*)&Ts[sr][sseg * 16 + c * 4] =
        (f32x4){v0.x + v1.x, v0.y + v1.y, v0.z + v1.z, v0.w + v1.w};
  }
  if (t < 32) rs[t] = sqp[r0 + t] + sqp[8192 + r0 + t];
  __syncthreads();

  int rp = t >> 4, cg2 = t & 15;
  int ra = 2 * rp, rb = ra + 1;
  int c0 = cg2 * 8;
  float ya[8] = {0, 0, 0, 0, 0, 0, 0, 0};
  float yb[8] = {0, 0, 0, 0, 0, 0, 0, 0};
#pragma unroll 4
  for (int j = 0; j < 128; ++j) {
    float tav = Ts[ra][j];
    float tbv = Ts[rb][j];
    float4 v0 = *(const float4*)(Minv + j * LATENT + c0);
    float4 v1 = *(const float4*)(Minv + j * LATENT + c0 + 4);
    ya[0] = fmaf(tav, v0.x, ya[0]); ya[1] = fmaf(tav, v0.y, ya[1]);
    ya[2] = fmaf(tav, v0.z, ya[2]); ya[3] = fmaf(tav, v0.w, ya[3]);
    ya[4] = fmaf(tav, v1.x, ya[4]); ya[5] = fmaf(tav, v1.y, ya[5]);
    ya[6] = fmaf(tav, v1.z, ya[6]); ya[7] = fmaf(tav, v1.w, ya[7]);
    yb[0] = fmaf(tbv, v0.x, yb[0]); yb[1] = fmaf(tbv, v0.y, yb[1]);
    yb[2] = fmaf(tbv, v0.z, yb[2]); yb[3] = fmaf(tbv, v0.w, yb[3]);
    yb[4] = fmaf(tbv, v1.x, yb[4]); yb[5] = fmaf(tbv, v1.y, yb[5]);
    yb[6] = fmaf(tbv, v1.z, yb[6]); yb[7] = fmaf(tbv, v1.w, yb[7]);
  }
  float q0 = 0.f, q1 = 0.f;
#pragma unroll
  for (int c = 0; c < 8; ++c) {
    q0 = fmaf(ya[c], Ts[ra][c0 + c], q0);
    q1 = fmaf(yb[c], Ts[rb][c0 + c], q1);
  }
  q0 += __shfl_xor(q0, 1); q0 += __shfl_xor(q0, 2);
  q0 += __shfl_xor(q0, 4); q0 += __shfl_xor(q0, 8);
  q1 += __shfl_xor(q1, 1); q1 += __shfl_xor(q1, 2);
  q1 += __shfl_xor(q1, 4); q1 += __shfl_xor(q1, 8);
  if (cg2 == 0) {
    float cc = scal[0], is2 = scal[1];
    out[r0 + ra] = cc - 0.5f * is2 * (rs[ra] - q0);
    out[r0 + rb] = cc - 0.5f * is2 * (rs[rb] - q1);
  }
}

// ---------------------------------------------------------------------------
extern "C" void kernel_launch(void* const* d_in, const int* in_sizes, int n_in,
                              void* d_out, int out_size, void* d_ws, size_t ws_size,
                              hipStream_t stream) {
  (void)in_sizes; (void)n_in; (void)out_size; (void)ws_size;
  const float* ex   = (const float*)d_in[0];
  const float* W    = (const float*)d_in[1];
  const float* lv   = (const float*)d_in[2];
  const float* mean = (const float*)d_in[3];
  float* out = (float*)d_out;

  // ws: M(16384f) | scal(64f) | Tp(2x1048576f) | sqp(2x8192f) | Wt(393216 bf16)
  // total 9,306,368 B (rounds 5-7 verified). Mp aliases Tp (consumed first).
  float* M = (float*)d_ws;
  float* scal = M + 16384;
  float* Tp = scal + 64;
  float* sqp = Tp + 2097152;
  unsigned short* Wt = (unsigned short*)(sqp + 16384);
  float* Mp = Tp;

  k_prep<<<48, 256, 0, stream>>>(W, Mp, Wt);
  k_red<<<64, 256, 0, stream>>>(Mp, M);
  k_gemm<<<513, 512, 0, stream>>>(ex, mean, Wt, M, scal, lv, Tp, sqp);
  k_epi<<<256, 256, 0, stream>>>(Tp, sqp, M, scal, out);
}

// Round 9
// 246.632 us; speedup vs baseline: 2.9416x; 2.9416x over previous
//
#include <hip/hip_runtime.h>
#include <hip/hip_bf16.h>

#define N_FEAT 3072
#define LATENT 128
#define LOG2PI 1.8378770664093453f

typedef __attribute__((ext_vector_type(8))) short short8;
typedef __attribute__((ext_vector_type(4))) float f32x4;

__device__ __forceinline__ unsigned short f2bf(float x) {
  unsigned int u = __float_as_uint(x);
  u += 0x7FFFu + ((u >> 16) & 1u);
  return (unsigned short)(u >> 16);
}

typedef __attribute__((address_space(1))) const void gas_void;
typedef __attribute__((address_space(3))) void las_void;
__device__ __forceinline__ void gld_lds16(const void* g, void* s) {
  __builtin_amdgcn_global_load_lds((gas_void*)g, (las_void*)s, 16, 0, 0);
}

// ===========================================================================
// k_prep: blocks 0..47: Mp[b] = Wchunk^T Wchunk partial (direct store) +
//         Wt[n][k] = bf16(W[k][n])   (proven rounds 5/7)
// ===========================================================================
__global__ __launch_bounds__(256) void k_prep(const float* __restrict__ W,
                                              float* __restrict__ Mp,
                                              unsigned short* __restrict__ Wt) {
  __shared__ __align__(16) float Ws[64 * 128];
  int t = threadIdx.x;
  int k0 = blockIdx.x * 64;
  const float* src = W + (size_t)k0 * 128;
#pragma unroll
  for (int c = 0; c < 8; ++c)
    ((float4*)Ws)[t + 256 * c] = ((const float4*)src)[t + 256 * c];
  __syncthreads();
  int tr = t >> 4, tc = t & 15;
  float acc[8][8];
#pragma unroll
  for (int r = 0; r < 8; ++r)
#pragma unroll
    for (int c = 0; c < 8; ++c) acc[r][c] = 0.f;
#pragma unroll 2
  for (int k = 0; k < 64; ++k) {
    f32x4 a0 = *(f32x4*)&Ws[k * 128 + 8 * tr];
    f32x4 a1 = *(f32x4*)&Ws[k * 128 + 8 * tr + 4];
    f32x4 b0 = *(f32x4*)&Ws[k * 128 + 8 * tc];
    f32x4 b1 = *(f32x4*)&Ws[k * 128 + 8 * tc + 4];
    float av[8] = {a0.x, a0.y, a0.z, a0.w, a1.x, a1.y, a1.z, a1.w};
    float bv[8] = {b0.x, b0.y, b0.z, b0.w, b1.x, b1.y, b1.z, b1.w};
#pragma unroll
    for (int r = 0; r < 8; ++r)
#pragma unroll
      for (int c = 0; c < 8; ++c) acc[r][c] = fmaf(av[r], bv[c], acc[r][c]);
  }
  float* dst = Mp + (size_t)blockIdx.x * 16384 + (size_t)(8 * tr) * 128 + 8 * tc;
#pragma unroll
  for (int r = 0; r < 8; ++r) {
    *(f32x4*)(dst + r * 128) = (f32x4){acc[r][0], acc[r][1], acc[r][2], acc[r][3]};
    *(f32x4*)(dst + r * 128 + 4) = (f32x4){acc[r][4], acc[r][5], acc[r][6], acc[r][7]};
  }
  int n = t >> 1, h = t & 1;
  unsigned pk[16];
#pragma unroll
  for (int c = 0; c < 16; ++c)
    pk[c] = (unsigned)f2bf(Ws[(h * 32 + 2 * c) * 128 + n]) |
            ((unsigned)f2bf(Ws[(h * 32 + 2 * c + 1) * 128 + n]) << 16);
  uint4* wd = (uint4*)(Wt + (size_t)n * N_FEAT + k0 + h * 32);
#pragma unroll
  for (int c = 0; c < 4; ++c)
    wd[c] = make_uint4(pk[4 * c], pk[4 * c + 1], pk[4 * c + 2], pk[4 * c + 3]);
}

// ===========================================================================
// k_red: M = sum of 48 gram partials (proven)
// ===========================================================================
__global__ __launch_bounds__(256) void k_red(const float* __restrict__ Mp,
                                             float* __restrict__ M) {
  int i = blockIdx.x * 256 + threadIdx.x;
  float s = 0.f;
#pragma unroll
  for (int p = 0; p < 48; ++p) s += Mp[(size_t)p * 16384 + i];
  M[i] = s;
}

// ===========================================================================
// k_inv: ONE block, 256 threads, OWN register budget (launch_bounds(256,1)
// -> VGPR cap 512, a[8][8] fully in registers, NO SPILL — this was the
// round-8 (and latent rounds 0-7) killer: fused with the tile path the
// allocator gave 40-64 VGPRs and spilled the 64-float array to scratch.
// Gauss-Jordan of (M + sigma^2 I) in place, logdet -> scal.
// ===========================================================================
__global__ __launch_bounds__(256, 1) void k_inv(float* __restrict__ M,
                                                float* __restrict__ scal,
                                                const float* __restrict__ log_var) {
  __shared__ float PR[2][128], PC[2][128], DB[2], DG[128], RD[2];
  int t = threadIdx.x;
  int itr = t >> 4, itc = t & 15;
  float lv = log_var[0];
  float sig2 = expf(lv);
  float a[8][8];
  {
    const float* srcM = M + (size_t)(8 * itr) * 128 + 8 * itc;
#pragma unroll
    for (int r = 0; r < 8; ++r) {
      f32x4 v0 = *(const f32x4*)(srcM + r * 128);
      f32x4 v1 = *(const f32x4*)(srcM + r * 128 + 4);
      a[r][0] = v0.x; a[r][1] = v0.y; a[r][2] = v0.z; a[r][3] = v0.w;
      a[r][4] = v1.x; a[r][5] = v1.y; a[r][6] = v1.z; a[r][7] = v1.w;
    }
    if (itr == itc) {
#pragma unroll
      for (int r = 0; r < 8; ++r) a[r][r] += sig2;
    }
    if (itr == 0) {
#pragma unroll
      for (int c = 0; c < 8; ++c) PR[0][8 * itc + c] = a[0][c];
    }
    if (itc == 0) {
#pragma unroll
      for (int r = 0; r < 8; ++r) PC[0][8 * itr + r] = a[r][0];
    }
    if (t == 0) DB[0] = a[0][0];
  }
  __syncthreads();
  for (int kb = 0; kb < 16; ++kb) {
#pragma unroll
    for (int lk = 0; lk < 8; ++lk) {
      const int k = kb * 8 + lk;
      const int buf = k & 1;
      {
        float d = DB[buf];
        if (t == 0) DG[k] = d;
        float p = 1.0f / d;
        float pr[8], pc[8];
#pragma unroll
        for (int c = 0; c < 8; ++c) pr[c] = PR[buf][8 * itc + c] * p;
#pragma unroll
        for (int r = 0; r < 8; ++r) pc[r] = PC[buf][8 * itr + r];
#pragma unroll
        for (int r = 0; r < 8; ++r)
#pragma unroll
          for (int c = 0; c < 8; ++c) a[r][c] = fmaf(-pc[r], pr[c], a[r][c]);
        bool myrow = (itr == (k >> 3));
        bool mycol = (itc == (k >> 3));
        if (myrow) {
#pragma unroll
          for (int c = 0; c < 8; ++c) a[lk][c] = pr[c];
        }
        if (mycol) {
#pragma unroll
          for (int r = 0; r < 8; ++r) a[r][lk] = -p * pc[r];
        }
        if (myrow && mycol) a[lk][lk] = p;
        if (k + 1 < 128) {
          const int nb = buf ^ 1;
          const int nl = (lk + 1) & 7;
          const int nr = (k + 1) >> 3;
          if (itr == nr) {
#pragma unroll
            for (int c = 0; c < 8; ++c) PR[nb][8 * itc + c] = a[nl][c];
          }
          if (itc == nr) {
#pragma unroll
            for (int r = 0; r < 8; ++r) PC[nb][8 * itr + r] = a[r][nl];
          }
          if (itr == nr && itc == nr) DB[nb] = a[nl][nl];
        }
      }
      __syncthreads();
    }
  }
  {
    float* dst = M + (size_t)(8 * itr) * 128 + 8 * itc;
#pragma unroll
    for (int r = 0; r < 8; ++r) {
      f32x4 v0 = {a[r][0], a[r][1], a[r][2], a[r][3]};
      f32x4 v1 = {a[r][4], a[r][5], a[r][6], a[r][7]};
      *(f32x4*)(dst + r * 128) = v0;
      *(f32x4*)(dst + r * 128 + 4) = v1;
    }
  }
  float ld = 0.f;
  if (t < 128) ld = logf(DG[t]);
#pragma unroll
  for (int o = 1; o < 64; o <<= 1) ld += __shfl_xor(ld, o);
  if (t == 0) RD[0] = ld;
  if (t == 64) RD[1] = ld;
  __syncthreads();
  if (t == 0) {
    scal[0] = -0.5f * (N_FEAT * LOG2PI + (float)(N_FEAT - LATENT) * lv +
                       (RD[0] + RD[1]));
    scal[1] = expf(-lv);
  }
}

// ===========================================================================
// k_gemm: 512 FLAT tile blocks (no inverse, no dual). One 32-row x K-half
// tile each: 512 thr, BK=128, 12 iters, double-buffered A+B LDS (80 KB ->
// 2 blocks/CU, grid exactly resident), B via global_load_lds with
// pre-inverse-swizzled source, counted vmcnt(8) across raw barriers,
// 2-deep A register prefetch.  (round-7-proven body, 36 us/tile measured)
// ===========================================================================
__global__ __launch_bounds__(512, 4) void k_gemm(
    const float* __restrict__ ex, const float* __restrict__ mean,
    const unsigned short* __restrict__ Wt, float* __restrict__ Tp,
    float* __restrict__ sqp) {
  __shared__ __align__(16) unsigned short As[2][32][128];   // 16 KB
  __shared__ __align__(16) unsigned short Bs[2][128][128];  // 64 KB
  int t = threadIdx.x;
  int g = blockIdx.x;              // 0..511
  int rg = g & 255, half = g >> 8;
  int r0 = rg * 32;
  int tg0 = half * 12;
  int lane = t & 63, w = t >> 6;

  int arow = t >> 4, ag = t & 15;
  const float* ep = ex + (size_t)(r0 + arow) * N_FEAT + (size_t)tg0 * 128 + ag * 8;
  const float* mp = mean + (size_t)tg0 * 128 + ag * 8;
  int awoff = arow * 256 + ((ag & 8) + ((ag + arow) & 7)) * 16;

  int sp = lane & 15, rl = lane >> 4;
  const unsigned short* bsrc[4];
#pragma unroll
  for (int j = 0; j < 4; ++j) {
    int n = w * 16 + j * 4 + rl;
    int s = (sp & 8) | ((sp - n) & 7);
    bsrc[j] = Wt + (size_t)n * N_FEAT + (size_t)tg0 * 128 + s * 8;
  }
  char* ldsB0 = (char*)Bs + (size_t)w * 4096;
  char* ldsB1 = (char*)Bs + 32768 + (size_t)w * 4096;

  int fr = lane & 15, fq = lane >> 4;
  int aoff0[4], aoff1[4], boff[4];
#pragma unroll
  for (int kk = 0; kk < 4; ++kk) {
    int sI = kk * 4 + fq;
    aoff0[kk] = fr * 256 + ((sI & 8) + ((sI + fr) & 7)) * 16;
    int ar1 = 16 + fr;
    aoff1[kk] = ar1 * 256 + ((sI & 8) + ((sI + ar1) & 7)) * 16;
    int n = w * 16 + fr;
    boff[kk] = n * 256 + ((sI & 8) + ((sI + n) & 7)) * 16;
  }

  f32x4 acc0 = {0.f, 0.f, 0.f, 0.f}, acc1 = {0.f, 0.f, 0.f, 0.f};
  float sq = 0.f;
  float4 eA, eA2, mA, mA2;   // even tiles
  float4 eB, eB2, mB, mB2;   // odd tiles

  auto loadS0 = [&](int it) {
    const float* p = ep + (size_t)it * 128;
    const float* q = mp + (size_t)it * 128;
    eA = *(const float4*)p;  eA2 = *(const float4*)(p + 4);
    mA = *(const float4*)q;  mA2 = *(const float4*)(q + 4);
  };
  auto loadS1 = [&](int it) {
    const float* p = ep + (size_t)it * 128;
    const float* q = mp + (size_t)it * 128;
    eB = *(const float4*)p;  eB2 = *(const float4*)(p + 4);
    mB = *(const float4*)q;  mB2 = *(const float4*)(q + 4);
  };
  auto packS = [&](const float4& e, const float4& e2, const float4& m,
                   const float4& m2, int bufN) {
    float r0_ = e.x - m.x,   r1_ = e.y - m.y,   r2_ = e.z - m.z,   r3_ = e.w - m.w;
    float r4_ = e2.x - m2.x, r5_ = e2.y - m2.y, r6_ = e2.z - m2.z, r7_ = e2.w - m2.w;
    sq = fmaf(r0_, r0_, sq); sq = fmaf(r1_, r1_, sq);
    sq = fmaf(r2_, r2_, sq); sq = fmaf(r3_, r3_, sq);
    sq = fmaf(r4_, r4_, sq); sq = fmaf(r5_, r5_, sq);
    sq = fmaf(r6_, r6_, sq); sq = fmaf(r7_, r7_, sq);
    uint4 pa;
    pa.x = (unsigned)f2bf(r0_) | ((unsigned)f2bf(r1_) << 16);
    pa.y = (unsigned)f2bf(r2_) | ((unsigned)f2bf(r3_) << 16);
    pa.z = (unsigned)f2bf(r4_) | ((unsigned)f2bf(r5_) << 16);
    pa.w = (unsigned)f2bf(r6_) | ((unsigned)f2bf(r7_) << 16);
    *(uint4*)((char*)As + bufN * 8192 + awoff) = pa;
  };
  auto issueB = [&](int it, int bufN) {
    char* d = bufN ? ldsB1 : ldsB0;
#pragma unroll
    for (int j = 0; j < 4; ++j)
      gld_lds16(bsrc[j] + (size_t)it * 128, d + j * 1024);
  };
  auto mma = [&](int bufN) {
    char* Ab = (char*)As + bufN * 8192;
    char* Bb = (char*)Bs + bufN * 32768;
#pragma unroll
    for (int kk = 0; kk < 4; ++kk) {
      short8 a0 = *(const short8*)(Ab + aoff0[kk]);
      short8 a1 = *(const short8*)(Ab + aoff1[kk]);
      short8 b  = *(const short8*)(Bb + boff[kk]);
      acc0 = __builtin_amdgcn_mfma_f32_16x16x32_bf16(a0, b, acc0, 0, 0, 0);
      acc1 = __builtin_amdgcn_mfma_f32_16x16x32_bf16(a1, b, acc1, 0, 0, 0);
    }
  };

  // prologue: tiles 0,1 A-loaded; B(0) in flight; tile0 packed; tile2 A-loaded
  loadS0(0);
  loadS1(1);
  __builtin_amdgcn_sched_barrier(0);
  issueB(0, 0);
  packS(eA, eA2, mA, mA2, 0);
  loadS0(2);
  asm volatile("s_waitcnt lgkmcnt(0)" ::: "memory");
  __builtin_amdgcn_s_barrier();
  __builtin_amdgcn_sched_barrier(0);

#pragma unroll
  for (int j = 0; j < 5; ++j) {
    const int it0 = 2 * j;
    // even iteration it0, buf 0
    issueB(it0 + 1, 1);
    asm volatile("s_waitcnt vmcnt(8)" ::: "memory");
    __builtin_amdgcn_sched_barrier(0);
    mma(0);
    packS(eB, eB2, mB, mB2, 1);
    loadS1(it0 + 3 < 12 ? it0 + 3 : 11);
    asm volatile("s_waitcnt lgkmcnt(0)" ::: "memory");
    __builtin_amdgcn_s_barrier();
    __builtin_amdgcn_sched_barrier(0);
    // odd iteration it0+1, buf 1
    issueB(it0 + 2, 0);
    asm volatile("s_waitcnt vmcnt(8)" ::: "memory");
    __builtin_amdgcn_sched_barrier(0);
    mma(1);
    packS(eA, eA2, mA, mA2, 0);
    loadS0(it0 + 4 < 12 ? it0 + 4 : 11);
    asm volatile("s_waitcnt lgkmcnt(0)" ::: "memory");
    __builtin_amdgcn_s_barrier();
    __builtin_amdgcn_sched_barrier(0);
  }
  // iteration 10 (buf 0)
  issueB(11, 1);
  asm volatile("s_waitcnt vmcnt(8)" ::: "memory");
  __builtin_amdgcn_sched_barrier(0);
  mma(0);
  packS(eB, eB2, mB, mB2, 1);
  asm volatile("s_waitcnt lgkmcnt(0)" ::: "memory");
  __builtin_amdgcn_s_barrier();
  __builtin_amdgcn_sched_barrier(0);
  // iteration 11 (buf 1)
  asm volatile("s_waitcnt vmcnt(0)" ::: "memory");
  __builtin_amdgcn_sched_barrier(0);
  mma(1);

  // sumsq partial
  sq += __shfl_xor(sq, 1); sq += __shfl_xor(sq, 2);
  sq += __shfl_xor(sq, 4); sq += __shfl_xor(sq, 8);
  if (ag == 0) sqp[half * 8192 + r0 + arow] = sq;

  // Tp partial store (D layout col=lane&15, row=fq*4+reg)
  float* tp = Tp + (size_t)half * 1048576 +
              (size_t)(r0 + fq * 4) * 128 + w * 16 + fr;
#pragma unroll
  for (int ii = 0; ii < 4; ++ii) {
    tp[(size_t)ii * 128] = acc0[ii];
    tp[(size_t)ii * 128 + 2048] = acc1[ii];
  }
}

// ===========================================================================
// k_epi: 256 blocks x 32 rows: t = Tp0+Tp1; quad = t^T Minv t;
//        out = scal0 - 0.5*scal1*(sumsq - quad)   (proven)
// ===========================================================================
__global__ __launch_bounds__(256) void k_epi(const float* __restrict__ Tp,
                                             const float* __restrict__ sqp,
                                             const float* __restrict__ Minv,
                                             const float* __restrict__ scal,
                                             float* __restrict__ out) {
  __shared__ __align__(16) float Ts[32][132];
  __shared__ float rs[32];
  int t = threadIdx.x;
  int r0 = blockIdx.x * 32;
  int sr = t >> 3, sseg = t & 7;
  const float* tp0 = Tp + (size_t)(r0 + sr) * 128 + sseg * 16;
  const float* tp1 = tp0 + 1048576;
#pragma unroll
  for (int c = 0; c < 4; ++c) {
    float4 v0 = *(const float4*)(tp0 + c * 4);
    float4 v1 = *(const float4*)(tp1 + c * 4);
    *(f32x4*)&Ts[sr][sseg * 16 + c * 4] =
        (f32x4){v0.x + v1.x, v0.y + v1.y, v0.z + v1.z, v0.w + v1.w};
  }
  if (t < 32) rs[t] = sqp[r0 + t] + sqp[8192 + r0 + t];
  __syncthreads();

  int rp = t >> 4, cg2 = t & 15;
  int ra = 2 * rp, rb = ra + 1;
  int c0 = cg2 * 8;
  float ya[8] = {0, 0, 0, 0, 0, 0, 0, 0};
  float yb[8] = {0, 0, 0, 0, 0, 0, 0, 0};
#pragma unroll 4
  for (int j = 0; j < 128; ++j) {
    float tav = Ts[ra][j];
    float tbv = Ts[rb][j];
    float4 v0 = *(const float4*)(Minv + j * LATENT + c0);
    float4 v1 = *(const float4*)(Minv + j * LATENT + c0 + 4);
    ya[0] = fmaf(tav, v0.x, ya[0]); ya[1] = fmaf(tav, v0.y, ya[1]);
    ya[2] = fmaf(tav, v0.z, ya[2]); ya[3] = fmaf(tav, v0.w, ya[3]);
    ya[4] = fmaf(tav, v1.x, ya[4]); ya[5] = fmaf(tav, v1.y, ya[5]);
    ya[6] = fmaf(tav, v1.z, ya[6]); ya[7] = fmaf(tav, v1.w, ya[7]);
    yb[0] = fmaf(tbv, v0.x, yb[0]); yb[1] = fmaf(tbv, v0.y, yb[1]);
    yb[2] = fmaf(tbv, v0.z, yb[2]); yb[3] = fmaf(tbv, v0.w, yb[3]);
    yb[4] = fmaf(tbv, v1.x, yb[4]); yb[5] = fmaf(tbv, v1.y, yb[5]);
    yb[6] = fmaf(tbv, v1.z, yb[6]); yb[7] = fmaf(tbv, v1.w, yb[7]);
  }
  float q0 = 0.f, q1 = 0.f;
#pragma unroll
  for (int c = 0; c < 8; ++c) {
    q0 = fmaf(ya[c], Ts[ra][c0 + c], q0);
    q1 = fmaf(yb[c], Ts[rb][c0 + c], q1);
  }
  q0 += __shfl_xor(q0, 1); q0 += __shfl_xor(q0, 2);
  q0 += __shfl_xor(q0, 4); q0 += __shfl_xor(q0, 8);
  q1 += __shfl_xor(q1, 1); q1 += __shfl_xor(q1, 2);
  q1 += __shfl_xor(q1, 4); q1 += __shfl_xor(q1, 8);
  if (cg2 == 0) {
    float cc = scal[0], is2 = scal[1];
    out[r0 + ra] = cc - 0.5f * is2 * (rs[ra] - q0);
    out[r0 + rb] = cc - 0.5f * is2 * (rs[rb] - q1);
  }
}

// ---------------------------------------------------------------------------
extern "C" void kernel_launch(void* const* d_in, const int* in_sizes, int n_in,
                              void* d_out, int out_size, void* d_ws, size_t ws_size,
                              hipStream_t stream) {
  (void)in_sizes; (void)n_in; (void)out_size; (void)ws_size;
  const float* ex   = (const float*)d_in[0];
  const float* W    = (const float*)d_in[1];
  const float* lv   = (const float*)d_in[2];
  const float* mean = (const float*)d_in[3];
  float* out = (float*)d_out;

  // ws: M(16384f) | scal(64f) | Tp(2x1048576f) | sqp(2x8192f) | Wt(393216 bf16)
  // total 9,306,368 B (rounds 5-8 verified). Mp aliases Tp (consumed first).
  float* M = (float*)d_ws;
  float* scal = M + 16384;
  float* Tp = scal + 64;
  float* sqp = Tp + 2097152;
  unsigned short* Wt = (unsigned short*)(sqp + 16384);
  float* Mp = Tp;

  k_prep<<<48, 256, 0, stream>>>(W, Mp, Wt);
  k_red<<<64, 256, 0, stream>>>(Mp, M);
  k_inv<<<1, 256, 0, stream>>>(M, scal, lv);
  k_gemm<<<512, 512, 0, stream>>>(ex, mean, Wt, Tp, sqp);
  k_epi<<<256, 256, 0, stream>>>(Tp, sqp, M, scal, out);
}

// Round 11
// 234.482 us; speedup vs baseline: 3.0940x; 1.0518x over previous
//
#include <hip/hip_runtime.h>
#include <hip/hip_bf16.h>

#define N_FEAT 3072
#define LATENT 128
#define LOG2PI 1.8378770664093453f

typedef __attribute__((ext_vector_type(8))) short short8;
typedef __attribute__((ext_vector_type(4))) float f32x4;

__device__ __forceinline__ unsigned short f2bf(float x) {
  unsigned int u = __float_as_uint(x);
  u += 0x7FFFu + ((u >> 16) & 1u);
  return (unsigned short)(u >> 16);
}

typedef __attribute__((address_space(1))) const void gas_void;
typedef __attribute__((address_space(3))) void las_void;
__device__ __forceinline__ void gld_lds16(const void* g, void* s) {
  __builtin_amdgcn_global_load_lds((gas_void*)g, (las_void*)s, 16, 0, 0);
}

// ===========================================================================
// k_prep: blocks 0..47: Mp[b] = Wchunk^T Wchunk partial (direct store) +
//         Wt[n][k] = bf16(W[k][n])   (proven rounds 5/7/9)
// ===========================================================================
__global__ __launch_bounds__(256) void k_prep(const float* __restrict__ W,
                                              float* __restrict__ Mp,
                                              unsigned short* __restrict__ Wt) {
  __shared__ __align__(16) float Ws[64 * 128];
  int t = threadIdx.x;
  int k0 = blockIdx.x * 64;
  const float* src = W + (size_t)k0 * 128;
#pragma unroll
  for (int c = 0; c < 8; ++c)
    ((float4*)Ws)[t + 256 * c] = ((const float4*)src)[t + 256 * c];
  __syncthreads();
  int tr = t >> 4, tc = t & 15;
  float acc[8][8];
#pragma unroll
  for (int r = 0; r < 8; ++r)
#pragma unroll
    for (int c = 0; c < 8; ++c) acc[r][c] = 0.f;
#pragma unroll 2
  for (int k = 0; k < 64; ++k) {
    f32x4 a0 = *(f32x4*)&Ws[k * 128 + 8 * tr];
    f32x4 a1 = *(f32x4*)&Ws[k * 128 + 8 * tr + 4];
    f32x4 b0 = *(f32x4*)&Ws[k * 128 + 8 * tc];
    f32x4 b1 = *(f32x4*)&Ws[k * 128 + 8 * tc + 4];
    float av[8] = {a0.x, a0.y, a0.z, a0.w, a1.x, a1.y, a1.z, a1.w};
    float bv[8] = {b0.x, b0.y, b0.z, b0.w, b1.x, b1.y, b1.z, b1.w};
#pragma unroll
    for (int r = 0; r < 8; ++r)
#pragma unroll
      for (int c = 0; c < 8; ++c) acc[r][c] = fmaf(av[r], bv[c], acc[r][c]);
  }
  float* dst = Mp + (size_t)blockIdx.x * 16384 + (size_t)(8 * tr) * 128 + 8 * tc;
#pragma unroll
  for (int r = 0; r < 8; ++r) {
    *(f32x4*)(dst + r * 128) = (f32x4){acc[r][0], acc[r][1], acc[r][2], acc[r][3]};
    *(f32x4*)(dst + r * 128 + 4) = (f32x4){acc[r][4], acc[r][5], acc[r][6], acc[r][7]};
  }
  int n = t >> 1, h = t & 1;
  unsigned pk[16];
#pragma unroll
  for (int c = 0; c < 16; ++c)
    pk[c] = (unsigned)f2bf(Ws[(h * 32 + 2 * c) * 128 + n]) |
            ((unsigned)f2bf(Ws[(h * 32 + 2 * c + 1) * 128 + n]) << 16);
  uint4* wd = (uint4*)(Wt + (size_t)n * N_FEAT + k0 + h * 32);
#pragma unroll
  for (int c = 0; c < 4; ++c)
    wd[c] = make_uint4(pk[4 * c], pk[4 * c + 1], pk[4 * c + 2], pk[4 * c + 3]);
}

// ===========================================================================
// k_red: M = sum of 48 gram partials (proven)
// ===========================================================================
__global__ __launch_bounds__(256) void k_red(const float* __restrict__ Mp,
                                             float* __restrict__ M) {
  int i = blockIdx.x * 256 + threadIdx.x;
  float s = 0.f;
#pragma unroll
  for (int p = 0; p < 48; ++p) s += Mp[(size_t)p * 16384 + i];
  M[i] = s;
}

// ===========================================================================
// inverse512: Gauss-Jordan of (M + sigma^2 I), logdet -> scal.
// Register-lean for fusion: 512 threads, a[4][8] = 32 floats/thread.
// Thread t -> rows 4*itr..+3 (itr=t>>4), cols 8*itc..+7 (itc=t&15).
// All a[][] indices compile-time under the unrolled lk loop.
// ===========================================================================
__device__ __forceinline__ void inverse512(float* sh, int t, float* M,
                                           float* scal,
                                           const float* log_var) {
  float* PR = sh;        // [2][128] pivot row
  float* PC = sh + 256;  // [2][128] pivot col
  float* DB = sh + 512;  // [2] pivot diag
  float* DG = sh + 514;  // [128] diag history
  float* RD = sh + 642;  // [2] logdet partials
  int itr = t >> 4, itc = t & 15;
  float lv = log_var[0];
  float sig2 = expf(lv);
  float a[4][8];
  const float* srcM = M + (size_t)(4 * itr) * 128 + 8 * itc;
#pragma unroll
  for (int r = 0; r < 4; ++r) {
    f32x4 v0 = *(const f32x4*)(srcM + r * 128);
    f32x4 v1 = *(const f32x4*)(srcM + r * 128 + 4);
    a[r][0] = v0.x; a[r][1] = v0.y; a[r][2] = v0.z; a[r][3] = v0.w;
    a[r][4] = v1.x; a[r][5] = v1.y; a[r][6] = v1.z; a[r][7] = v1.w;
  }
#pragma unroll
  for (int r = 0; r < 4; ++r) {
    int lc = 4 * itr + r - 8 * itc;   // diagonal element's local col
    if (lc >= 0 && lc < 8) {
#pragma unroll
      for (int c = 0; c < 8; ++c)
        if (c == lc) a[r][c] += sig2;
    }
  }
  if (itr == 0) {
#pragma unroll
    for (int c = 0; c < 8; ++c) PR[8 * itc + c] = a[0][c];
  }
  if (itc == 0) {
#pragma unroll
    for (int r = 0; r < 4; ++r) PC[4 * itr + r] = a[r][0];
  }
  if (t == 0) DB[0] = a[0][0];
  __syncthreads();
  for (int kb = 0; kb < 16; ++kb) {
#pragma unroll
    for (int lk = 0; lk < 8; ++lk) {
      const int k = kb * 8 + lk;
      const int buf = lk & 1;
      float d = DB[buf];
      if (t == 0) DG[k] = d;
      float p = 1.0f / d;
      float pr[8], pc[4];
#pragma unroll
      for (int c = 0; c < 8; ++c) pr[c] = PR[buf * 128 + 8 * itc + c] * p;
#pragma unroll
      for (int r = 0; r < 4; ++r) pc[r] = PC[buf * 128 + 4 * itr + r];
#pragma unroll
      for (int r = 0; r < 4; ++r)
#pragma unroll
        for (int c = 0; c < 8; ++c) a[r][c] = fmaf(-pc[r], pr[c], a[r][c]);
      bool myrow = (itr == (k >> 2));
      bool mycol = (itc == (k >> 3));
      if (myrow) {
#pragma unroll
        for (int c = 0; c < 8; ++c) a[lk & 3][c] = pr[c];
      }
      if (mycol) {
#pragma unroll
        for (int r = 0; r < 4; ++r) a[r][lk] = -p * pc[r];
      }
      if (myrow && mycol) a[lk & 3][lk] = p;
      if (k + 1 < 128) {
        const int nb = buf ^ 1;
        const int nk = k + 1;
        const int nl3 = (lk + 1) & 3;   // pivot k+1 local row (compile-time)
        const int nl7 = (lk + 1) & 7;   // pivot k+1 local col (compile-time)
        if (itr == (nk >> 2)) {
#pragma unroll
          for (int c = 0; c < 8; ++c) PR[nb * 128 + 8 * itc + c] = a[nl3][c];
        }
        if (itc == (nk >> 3)) {
#pragma unroll
          for (int r = 0; r < 4; ++r) PC[nb * 128 + 4 * itr + r] = a[r][nl7];
        }
        if (itr == (nk >> 2) && itc == (nk >> 3)) DB[nb] = a[nl3][nl7];
      }
      __syncthreads();
    }
  }
  {
    float* dst = M + (size_t)(4 * itr) * 128 + 8 * itc;
#pragma unroll
    for (int r = 0; r < 4; ++r) {
      f32x4 v0 = {a[r][0], a[r][1], a[r][2], a[r][3]};
      f32x4 v1 = {a[r][4], a[r][5], a[r][6], a[r][7]};
      *(f32x4*)(dst + r * 128) = v0;
      *(f32x4*)(dst + r * 128 + 4) = v1;
    }
  }
  float ld = 0.f;
  if (t < 128) ld = logf(DG[t]);
#pragma unroll
  for (int o = 1; o < 64; o <<= 1) ld += __shfl_xor(ld, o);
  if (t == 0) RD[0] = ld;
  if (t == 64) RD[1] = ld;
  __syncthreads();
  if (t == 0) {
    scal[0] = -0.5f * (N_FEAT * LOG2PI + (float)(N_FEAT - LATENT) * lv +
                       (RD[0] + RD[1]));
    scal[1] = expf(-lv);
  }
}

// ===========================================================================
// k_gemm: 513 blocks, 48 KB LDS -> 3 blocks/CU -> all co-resident at t=0.
//   blocks 0..511: one flat 32-row x K-half tile (round-8-proven loop:
//     A double-buffered + 1 barrier/iter; B SINGLE-buffered wave-private —
//     wave w DMAs AND reads only rows w*16..+15, synced by per-wave
//     lgkmcnt(0) [reads drained before re-DMA] and vmcnt(4) [DMA landed]).
//   block 512: register-lean inverse, fully overlapped with the tiles.
// launch_bounds(512,4): VGPR cap 128 (round 8's (512,6) forced 40 -> spill).
// ===========================================================================
__global__ __launch_bounds__(512, 4) void k_gemm(
    const float* __restrict__ ex, const float* __restrict__ mean,
    const unsigned short* __restrict__ Wt, float* __restrict__ M,
    float* __restrict__ scal, const float* __restrict__ lv,
    float* __restrict__ Tp, float* __restrict__ sqp) {
  __shared__ __align__(16) char smem[49152];
  int t = threadIdx.x;
  if (blockIdx.x == 512) {
    inverse512((float*)smem, t, M, scal, lv);
    return;
  }
  char* As = smem;            // [2][32][128] ushort = 16 KB
  char* Bs = smem + 16384;    // [128][128] ushort = 32 KB (single buffer)
  int g = blockIdx.x;         // 0..511
  int rg = g & 255, half = g >> 8;
  int r0 = rg * 32;
  int tg0 = half * 12;
  int lane = t & 63, w = t >> 6;

  int arow = t >> 4, ag = t & 15;
  const float* ep = ex + (size_t)(r0 + arow) * N_FEAT + (size_t)tg0 * 128 + ag * 8;
  const float* mp = mean + (size_t)tg0 * 128 + ag * 8;
  int awoff = arow * 256 + ((ag & 8) + ((ag + arow) & 7)) * 16;

  int sp = lane & 15, rl = lane >> 4;
  const unsigned short* bsrc[4];
#pragma unroll
  for (int j = 0; j < 4; ++j) {
    int n = w * 16 + j * 4 + rl;
    int s = (sp & 8) | ((sp - n) & 7);
    bsrc[j] = Wt + (size_t)n * N_FEAT + (size_t)tg0 * 128 + s * 8;
  }
  char* ldsB = Bs + (size_t)w * 4096;   // wave-private 16-row region

  int fr = lane & 15, fq = lane >> 4;
  int aoff0[4], aoff1[4], boff[4];
#pragma unroll
  for (int kk = 0; kk < 4; ++kk) {
    int sI = kk * 4 + fq;
    aoff0[kk] = fr * 256 + ((sI & 8) + ((sI + fr) & 7)) * 16;
    int ar1 = 16 + fr;
    aoff1[kk] = ar1 * 256 + ((sI & 8) + ((sI + ar1) & 7)) * 16;
    int n = w * 16 + fr;
    boff[kk] = n * 256 + ((sI & 8) + ((sI + n) & 7)) * 16;
  }

  f32x4 acc0 = {0.f, 0.f, 0.f, 0.f}, acc1 = {0.f, 0.f, 0.f, 0.f};
  float sq = 0.f;
  float4 e, e2, m, m2;   // single A register set (consume-then-reload)

  auto loadA = [&](int it) {
    const float* p = ep + (size_t)it * 128;
    const float* q = mp + (size_t)it * 128;
    e  = *(const float4*)p;  e2 = *(const float4*)(p + 4);
    m  = *(const float4*)q;  m2 = *(const float4*)(q + 4);
  };
  auto packA = [&](int bufN) {
    float r0_ = e.x - m.x,   r1_ = e.y - m.y,   r2_ = e.z - m.z,   r3_ = e.w - m.w;
    float r4_ = e2.x - m2.x, r5_ = e2.y - m2.y, r6_ = e2.z - m2.z, r7_ = e2.w - m2.w;
    sq = fmaf(r0_, r0_, sq); sq = fmaf(r1_, r1_, sq);
    sq = fmaf(r2_, r2_, sq); sq = fmaf(r3_, r3_, sq);
    sq = fmaf(r4_, r4_, sq); sq = fmaf(r5_, r5_, sq);
    sq = fmaf(r6_, r6_, sq); sq = fmaf(r7_, r7_, sq);
    uint4 pa;
    pa.x = (unsigned)f2bf(r0_) | ((unsigned)f2bf(r1_) << 16);
    pa.y = (unsigned)f2bf(r2_) | ((unsigned)f2bf(r3_) << 16);
    pa.z = (unsigned)f2bf(r4_) | ((unsigned)f2bf(r5_) << 16);
    pa.w = (unsigned)f2bf(r6_) | ((unsigned)f2bf(r7_) << 16);
    *(uint4*)(As + bufN * 8192 + awoff) = pa;
  };
  auto issueB = [&](int it) {
#pragma unroll
    for (int j = 0; j < 4; ++j)
      gld_lds16(bsrc[j] + (size_t)it * 128, ldsB + j * 1024);
  };
  auto mma = [&](int bufA) {
    char* Ab = As + bufA * 8192;
#pragma unroll
    for (int kk = 0; kk < 4; ++kk) {
      short8 a0 = *(const short8*)(Ab + aoff0[kk]);
      short8 a1 = *(const short8*)(Ab + aoff1[kk]);
      short8 b  = *(const short8*)(Bs + boff[kk]);
      acc0 = __builtin_amdgcn_mfma_f32_16x16x32_bf16(a0, b, acc0, 0, 0, 0);
      acc1 = __builtin_amdgcn_mfma_f32_16x16x32_bf16(a1, b, acc1, 0, 0, 0);
    }
  };

  // ---- prologue: A(0) packed to buf0; B(0) DMA; A(1) regs in flight ----
  loadA(0);
  packA(0);                                 // implicit wait on loadA(0)
  __builtin_amdgcn_sched_barrier(0);
  issueB(0);                                // 4 DMA
  loadA(1);
  asm volatile("s_waitcnt lgkmcnt(0)" ::: "memory");
  __builtin_amdgcn_s_barrier();
  asm volatile("s_waitcnt vmcnt(4)" ::: "memory");  // B(0) landed; A(1) in flight
  __builtin_amdgcn_sched_barrier(0);

  // ---- main loop: single barrier/iter; B synced per-wave by counts ----
#pragma unroll
  for (int it = 0; it < 11; ++it) {
    mma(it & 1);                            // reads A buf, own B rows
    asm volatile("s_waitcnt lgkmcnt(0)" ::: "memory");  // B reads drained
    __builtin_amdgcn_sched_barrier(0);
    issueB(it + 1);                         // overwrite own B region
    __builtin_amdgcn_sched_barrier(0);      // keep DMA issue before pack
    packA((it + 1) & 1);                    // waits loadA(it+1) via vmcnt(4)
    loadA(it + 2 <= 11 ? it + 2 : 11);      // clamped tail reload (harmless)
    asm volatile("s_waitcnt lgkmcnt(0)" ::: "memory");
    __builtin_amdgcn_s_barrier();
    asm volatile("s_waitcnt vmcnt(4)" ::: "memory");  // B(it+1) landed
    __builtin_amdgcn_sched_barrier(0);
  }
  mma(1);                                   // tile 11 (buf 1)

  // ---- sumsq partial ----
  sq += __shfl_xor(sq, 1); sq += __shfl_xor(sq, 2);
  sq += __shfl_xor(sq, 4); sq += __shfl_xor(sq, 8);
  if (ag == 0) sqp[half * 8192 + r0 + arow] = sq;

  // ---- Tp partial store (D layout col=lane&15, row=fq*4+reg) ----
  float* tp = Tp + (size_t)half * 1048576 +
              (size_t)(r0 + fq * 4) * 128 + w * 16 + fr;
#pragma unroll
  for (int ii = 0; ii < 4; ++ii) {
    tp[(size_t)ii * 128] = acc0[ii];
    tp[(size_t)ii * 128 + 2048] = acc1[ii];
  }
}

// ===========================================================================
// k_epi: 256 blocks x 32 rows: t = Tp0+Tp1; quad = t^T Minv t;
//        out = scal0 - 0.5*scal1*(sumsq - quad)   (proven)
// ===========================================================================
__global__ __launch_bounds__(256) void k_epi(const float* __restrict__ Tp,
                                             const float* __restrict__ sqp,
                                             const float* __restrict__ Minv,
                                             const float* __restrict__ scal,
                                             float* __restrict__ out) {
  __shared__ __align__(16) float Ts[32][132];
  __shared__ float rs[32];
  int t = threadIdx.x;
  int r0 = blockIdx.x * 32;
  int sr = t >> 3, sseg = t & 7;
  const float* tp0 = Tp + (size_t)(r0 + sr) * 128 + sseg * 16;
  const float* tp1 = tp0 + 1048576;
#pragma unroll
  for (int c = 0; c < 4; ++c) {
    float4 v0 = *(const float4*)(tp0 + c * 4);
    float4 v1 = *(const float4*)(tp1 + c * 4);
    *(f32x4*)&Ts[sr][sseg * 16 + c * 4] =
        (f32x4){v0.x + v1.x, v0.y + v1.y, v0.z + v1.z, v0.w + v1.w};
  }
  if (t < 32) rs[t] = sqp[r0 + t] + sqp[8192 + r0 + t];
  __syncthreads();

  int rp = t >> 4, cg2 = t & 15;
  int ra = 2 * rp, rb = ra + 1;
  int c0 = cg2 * 8;
  float ya[8] = {0, 0, 0, 0, 0, 0, 0, 0};
  float yb[8] = {0, 0, 0, 0, 0, 0, 0, 0};
#pragma unroll 4
  for (int j = 0; j < 128; ++j) {
    float tav = Ts[ra][j];
    float tbv = Ts[rb][j];
    float4 v0 = *(const float4*)(Minv + j * LATENT + c0);
    float4 v1 = *(const float4*)(Minv + j * LATENT + c0 + 4);
    ya[0] = fmaf(tav, v0.x, ya[0]); ya[1] = fmaf(tav, v0.y, ya[1]);
    ya[2] = fmaf(tav, v0.z, ya[2]); ya[3] = fmaf(tav, v0.w, ya[3]);
    ya[4] = fmaf(tav, v1.x, ya[4]); ya[5] = fmaf(tav, v1.y, ya[5]);
    ya[6] = fmaf(tav, v1.z, ya[6]); ya[7] = fmaf(tav, v1.w, ya[7]);
    yb[0] = fmaf(tbv, v0.x, yb[0]); yb[1] = fmaf(tbv, v0.y, yb[1]);
    yb[2] = fmaf(tbv, v0.z, yb[2]); yb[3] = fmaf(tbv, v0.w, yb[3]);
    yb[4] = fmaf(tbv, v1.x, yb[4]); yb[5] = fmaf(tbv, v1.y, yb[5]);
    yb[6] = fmaf(tbv, v1.z, yb[6]); yb[7] = fmaf(tbv, v1.w, yb[7]);
  }
  float q0 = 0.f, q1 = 0.f;
#pragma unroll
  for (int c = 0; c < 8; ++c) {
    q0 = fmaf(ya[c], Ts[ra][c0 + c], q0);
    q1 = fmaf(yb[c], Ts[rb][c0 + c], q1);
  }
  q0 += __shfl_xor(q0, 1); q0 += __shfl_xor(q0, 2);
  q0 += __shfl_xor(q0, 4); q0 += __shfl_xor(q0, 8);
  q1 += __shfl_xor(q1, 1); q1 += __shfl_xor(q1, 2);
  q1 += __shfl_xor(q1, 4); q1 += __shfl_xor(q1, 8);
  if (cg2 == 0) {
    float cc = scal[0], is2 = scal[1];
    out[r0 + ra] = cc - 0.5f * is2 * (rs[ra] - q0);
    out[r0 + rb] = cc - 0.5f * is2 * (rs[rb] - q1);
  }
}

// ---------------------------------------------------------------------------
extern "C" void kernel_launch(void* const* d_in, const int* in_sizes, int n_in,
                              void* d_out, int out_size, void* d_ws, size_t ws_size,
                              hipStream_t stream) {
  (void)in_sizes; (void)n_in; (void)out_size; (void)ws_size;
  const float* ex   = (const float*)d_in[0];
  const float* W    = (const float*)d_in[1];
  const float* lv   = (const float*)d_in[2];
  const float* mean = (const float*)d_in[3];
  float* out = (float*)d_out;

  // ws: M(16384f) | scal(64f) | Tp(2x1048576f) | sqp(2x8192f) | Wt(393216 bf16)
  // total 9,306,368 B (rounds 5-9 verified). Mp aliases Tp (consumed first).
  float* M = (float*)d_ws;
  float* scal = M + 16384;
  float* Tp = scal + 64;
  float* sqp = Tp + 2097152;
  unsigned short* Wt = (unsigned short*)(sqp + 16384);
  float* Mp = Tp;

  k_prep<<<48, 256, 0, stream>>>(W, Mp, Wt);
  k_red<<<64, 256, 0, stream>>>(Mp, M);
  k_gemm<<<513, 512, 0, stream>>>(ex, mean, Wt, M, scal, lv, Tp, sqp);
  k_epi<<<256, 256, 0, stream>>>(Tp, sqp, M, scal, out);
}